// Round 9
// baseline (490.463 us; speedup 1.0000x reference)
//
#include <hip/hip_runtime.h>
#include <hip/hip_bf16.h>
#include <cstdint>

#define BB 64
#define TT 2048
#define FD 256
#define UU 32

// ---------------------------------------------------------------------------
// Kernel 1 v4: pot[b,t,u] = dot(x[b,t,:], K[:,u]) + bias[u] (+ boundaries)
// r8: v3 (x from global, K in 32KB LDS, 1-wave blocks, grid 1024) = 50.8 us.
// Pipe model says the floor is the per-CU LDS pipe (~49k cyc = 20.5 us); the
// 2x gap is latency exposure at 1 wave/SIMD. v4: 2-wave blocks share one Kt
// (32KB -> 5 blocks/CU = 10 waves/CU = 2.5 waves/SIMD), grid 512. Per-wave
// inner code identical to v3 -> pot bit-identical. Wave w of block B owns
// tiles B*2+w + 1024*r, r=0..3.
// ---------------------------------------------------------------------------
__global__ __launch_bounds__(128) void potentials_kernel(
    const float* __restrict__ x, const float* __restrict__ K,
    const float* __restrict__ bias, const float* __restrict__ lb,
    const float* __restrict__ rb, float* __restrict__ pot)
{
    __shared__ __align__(16) float Kt[8192];   // 32 KB: [32 u][256 f], swizzled

    const int tid  = threadIdx.x;
    const int wv   = tid >> 6;       // wave 0..1
    const int lane = tid & 63;
    const int ug = lane & 7;
    const int rg = lane >> 3;

    // Stage K (once per block, both waves): K is [f][u] -> Kt[u][f] swizzled.
    for (int j = 0; j < 64; ++j) {
        const int e = j * 128 + tid;
        const int f = e >> 5;
        const int u = e & 31;
        Kt[u * 256 + (((f >> 2) ^ (u & 7)) << 2) + (f & 3)] = K[e];
    }
    __syncthreads();                  // Kt read-only afterwards — only barrier

    float bu[4], lu4[4], ru4[4];
    #pragma unroll
    for (int m = 0; m < 4; ++m) {
        bu[m]  = bias[ug + 8 * m];
        lu4[m] = lb[ug + 8 * m];
        ru4[m] = rb[ug + 8 * m];
    }

    const int wid = blockIdx.x * 2 + wv;   // 0..1023
    for (int tile = wid; tile < (BB * TT) / 32; tile += 1024) {
        const int row0 = tile * 32;

        float acc[4][4];
        #pragma unroll
        for (int i = 0; i < 4; ++i)
            #pragma unroll
            for (int m = 0; m < 4; ++m) acc[i][m] = 0.f;

        #pragma unroll 4
        for (int q = 0; q < 64; ++q) {
            float4 xq[4], kq[4];
            #pragma unroll
            for (int i = 0; i < 4; ++i)
                xq[i] = *(const float4*)(x + (size_t)(row0 + rg + 8 * i) * FD + q * 4);
            #pragma unroll
            for (int m = 0; m < 4; ++m)
                kq[m] = *(const float4*)&Kt[(ug + 8 * m) * 256 + ((q ^ ug) << 2)];
            #pragma unroll
            for (int i = 0; i < 4; ++i)
                #pragma unroll
                for (int m = 0; m < 4; ++m) {
                    acc[i][m] += xq[i].x * kq[m].x;
                    acc[i][m] += xq[i].y * kq[m].y;
                    acc[i][m] += xq[i].z * kq[m].z;
                    acc[i][m] += xq[i].w * kq[m].w;
                }
        }

        #pragma unroll
        for (int i = 0; i < 4; ++i) {
            const int row = row0 + rg + 8 * i;
            const int t = row & (TT - 1);
            #pragma unroll
            for (int m = 0; m < 4; ++m) {
                pot[(size_t)row * UU + ug + 8 * m] =
                    acc[i][m] + bu[m] + (t == 0 ? lu4[m] : 0.f)
                              + (t == TT - 1 ? ru4[m] : 0.f);
            }
        }
    }
}

// ---------------------------------------------------------------------------
// quad_perm [1,0,3,2]: swap adjacent lane pairs via DPP (VALU pipe, no LDS).
// ---------------------------------------------------------------------------
__device__ __forceinline__ float quad_swap(float v) {
    const int i = __float_as_int(v);
    const int r = __builtin_amdgcn_update_dpp(i, i, 0xB1, 0xF, 0xF, true);
    return __int_as_float(r);
}

// ---------------------------------------------------------------------------
// Kernel 2: values-only serial forward — v1 structure (195.8 us verified)
// with ONE change: the 16-way max tree is max3-shaped (15 fmax -> 8 ops,
// clang fuses fmaxf(fmaxf(a,b),c) to v_max3_f32; depth 4 -> 3). Max is
// exact under any association -> mm and chk bit-identical.
// ---------------------------------------------------------------------------
__global__ __launch_bounds__(64) void vit_values_kernel(
    const float* __restrict__ pot, const float* __restrict__ chain,
    float* __restrict__ chk)
{
    __shared__ __align__(16) float mbuf[32];

    const int lane = threadIdx.x;
    const int u = lane >> 1;
    const int q = lane & 1;
    const int qb = 16 * q;
    const int b = blockIdx.x;
    const float* pb = pot + (size_t)b * TT * UU;

    float cc[16];
    #pragma unroll
    for (int i = 0; i < 16; ++i) cc[i] = chain[(qb + i) * UU + u];

    float s[16];
    {
        const float4* s0 = (const float4*)(pb + qb);
        #pragma unroll
        for (int k = 0; k < 4; ++k) {
            const float4 v = s0[k];
            s[4*k+0] = v.x; s[4*k+1] = v.y; s[4*k+2] = v.z; s[4*k+3] = v.w;
        }
    }

    auto step = [&](float potv, int t) {
        float a[16];
        #pragma unroll
        for (int i = 0; i < 16; ++i) a[i] = s[i] + cc[i];
        // max3-shaped exact reduction: 8 ops, depth 3
        const float r0 = fmaxf(fmaxf(a[0],  a[1]),  a[2]);
        const float r1 = fmaxf(fmaxf(a[3],  a[4]),  a[5]);
        const float r2 = fmaxf(fmaxf(a[6],  a[7]),  a[8]);
        const float r3 = fmaxf(fmaxf(a[9],  a[10]), a[11]);
        const float r4 = fmaxf(fmaxf(a[12], a[13]), a[14]);
        const float r5 = fmaxf(fmaxf(r0, r1), r2);
        const float r6 = fmaxf(fmaxf(r3, r4), a[15]);
        const float pm = fmaxf(r5, r6);
        const float om = quad_swap(pm);          // other half's partial max
        const float mm = fmaxf(pm, om) + potv;   // exact max, single rounding

        mbuf[u] = mm;                            // both q-lanes write same value

        if ((t & 63) == 63)
            chk[((size_t)b * 33 + ((t >> 6) + 1)) * UU + u] = mm;

        const float4 x0 = *(const float4*)&mbuf[qb + 0];
        const float4 x1 = *(const float4*)&mbuf[qb + 4];
        const float4 x2 = *(const float4*)&mbuf[qb + 8];
        const float4 x3 = *(const float4*)&mbuf[qb + 12];
        s[0]=x0.x;  s[1]=x0.y;  s[2]=x0.z;  s[3]=x0.w;
        s[4]=x1.x;  s[5]=x1.y;  s[6]=x1.z;  s[7]=x1.w;
        s[8]=x2.x;  s[9]=x2.y;  s[10]=x2.z; s[11]=x2.w;
        s[12]=x3.x; s[13]=x3.y; s[14]=x3.z; s[15]=x3.w;
    };

    float pr[8], pn[8];
    #pragma unroll
    for (int j = 0; j < 8; ++j) pr[j] = pb[(1 + j) * UU + u];

    #pragma unroll 1
    for (int g = 0; g < 255; ++g) {
        #pragma unroll
        for (int j = 0; j < 8; ++j) {
            int tp = 9 + 8 * g + j;
            if (tp > TT - 1) tp = TT - 1;
            pn[j] = pb[tp * UU + u];
        }
        const int t0 = 1 + 8 * g;
        #pragma unroll
        for (int j = 0; j < 8; ++j)
            step(pr[j], t0 + j);
        #pragma unroll
        for (int j = 0; j < 8; ++j) pr[j] = pn[j];
    }
    // tail: t = 2041..2047 (includes final checkpoint wck = 32 at t = 2047)
    #pragma unroll
    for (int j = 0; j < 7; ++j)
        step(pr[j], 2041 + j);
}

// ---------------------------------------------------------------------------
// Kernel 3: parallel window recompute (unchanged, verified).
// ---------------------------------------------------------------------------
__global__ __launch_bounds__(64) void vit_window_kernel(
    const float* __restrict__ pot, const float* __restrict__ chain,
    const float* __restrict__ chk, unsigned char* __restrict__ Mg,
    unsigned char* __restrict__ bpg)
{
    __shared__ float potL[64 * 32];   // 8 KB: pot rows 64w .. 64w+63
    __shared__ float mbuf[32];

    const int lane = threadIdx.x;
    const int u = lane & 31;
    const int h = lane >> 5;
    const int hbase = 16 * h;
    const int w = blockIdx.x;
    const int b = blockIdx.y;
    const float* pb = pot + (size_t)b * TT * UU;
    const int r0 = 64 * w;

    {
        const float4* src = (const float4*)(pb + (size_t)r0 * UU);
        float4* dst = (float4*)potL;
        #pragma unroll
        for (int k = 0; k < 8; ++k) dst[lane + 64 * k] = src[lane + 64 * k];
    }
    __syncthreads();

    float cc[16];
    #pragma unroll
    for (int i = 0; i < 16; ++i) cc[i] = chain[(hbase + i) * UU + u];

    float s[16];
    if (w == 0) {
        #pragma unroll
        for (int i = 0; i < 16; ++i) s[i] = potL[hbase + i];          // state t=0
    } else {
        #pragma unroll
        for (int i = 0; i < 16; ++i) s[i] = chk[((size_t)b * 33 + w) * UU + hbase + i];
    }

    int orig = u;
    unsigned char* bb = bpg + (size_t)b * (TT - 1) * UU;

    const int tl0 = (w == 0) ? 1 : 0;
    #pragma unroll 1
    for (int tl = tl0; tl < 64; ++tl) {
        const int t = r0 + tl;
        const float potv = potL[tl * UU + u];

        float a[16];
        #pragma unroll
        for (int i = 0; i < 16; ++i) a[i] = s[i] + cc[i];

        // first-occurrence argmax: pairwise tree, right wins only if strictly >
        float v8[8]; int i8[8];
        #pragma unroll
        for (int i = 0; i < 8; ++i) {
            const bool c = a[2*i+1] > a[2*i];
            v8[i] = c ? a[2*i+1] : a[2*i];
            i8[i] = c ? (2*i+1) : (2*i);
        }
        float v4[4]; int i4[4];
        #pragma unroll
        for (int i = 0; i < 4; ++i) {
            const bool c = v8[2*i+1] > v8[2*i];
            v4[i] = c ? v8[2*i+1] : v8[2*i];
            i4[i] = c ? i8[2*i+1] : i8[2*i];
        }
        float v2[2]; int i2[2];
        #pragma unroll
        for (int i = 0; i < 2; ++i) {
            const bool c = v4[2*i+1] > v4[2*i];
            v2[i] = c ? v4[2*i+1] : v4[2*i];
            i2[i] = c ? i4[2*i+1] : i4[2*i];
        }
        const bool cf = v2[1] > v2[0];
        const float pv = cf ? v2[1] : v2[0];
        const int pidx = hbase + (cf ? i2[1] : i2[0]);

        const float opv = __shfl_xor(pv, 32, 64);
        const int   opi = __shfl_xor(pidx, 32, 64);
        const bool take = h ? (opv >= pv) : (opv > pv);   // tie -> lower half
        const int  mv   = take ? opi : pidx;
        const float mm  = fmaxf(pv, opv) + potv;

        if (h == 0) bb[(size_t)(t - 1) * UU + u] = (unsigned char)mv;
        orig = __shfl(orig, mv, 64);

        mbuf[u] = mm;
        const float4 x0 = *(const float4*)&mbuf[hbase + 0];
        const float4 x1 = *(const float4*)&mbuf[hbase + 4];
        const float4 x2 = *(const float4*)&mbuf[hbase + 8];
        const float4 x3 = *(const float4*)&mbuf[hbase + 12];
        s[0]=x0.x; s[1]=x0.y; s[2]=x0.z;  s[3]=x0.w;
        s[4]=x1.x; s[5]=x1.y; s[6]=x1.z;  s[7]=x1.w;
        s[8]=x2.x; s[9]=x2.y; s[10]=x2.z; s[11]=x2.w;
        s[12]=x3.x; s[13]=x3.y; s[14]=x3.z; s[15]=x3.w;
    }

    if (h == 0) Mg[(size_t)b * 1024 + w * UU + u] = (unsigned char)orig;
}

// ---------------------------------------------------------------------------
// Kernel 4: per-batch backtrack (unchanged, verified).
// ---------------------------------------------------------------------------
__global__ __launch_bounds__(64) void vit_backtrack_kernel(
    const float* __restrict__ chk, const unsigned char* __restrict__ Mg,
    const unsigned char* __restrict__ bpg, int* __restrict__ out)
{
    __shared__ __align__(16) unsigned char bp[(TT - 1) * UU];   // 65504 B

    const int lane = threadIdx.x;
    const int b = blockIdx.x;
    const unsigned char* bb = bpg + (size_t)b * (TT - 1) * UU;

    // stage bp: 4094 int4s
    #pragma unroll 4
    for (int i = 0; i < 64; ++i) {
        const int idx = i * 64 + lane;
        if (idx < 4094)
            ((int4*)bp)[idx] = ((const int4*)bb)[idx];
    }

    // last_tag = argmax_u chk[b][32][u], smallest u on tie
    float fv = (lane < 32) ? chk[((size_t)b * 33 + 32) * UU + lane] : -INFINITY;
    int fi = lane & 31;
    #pragma unroll
    for (int mask = 16; mask >= 1; mask >>= 1) {
        const float ov = __shfl_xor(fv, mask, 64);
        const int oi = __shfl_xor(fi, mask, 64);
        if (ov > fv || (ov == fv && oi < fi)) { fv = ov; fi = oi; }
    }
    int bt = __shfl(fi, 0, 64);

    // boundary walk over Mg (uniform addresses -> broadcast global loads)
    int my_btag = 0;
    #pragma unroll 1
    for (int w = 31; w >= 0; --w) {
        if (lane == w) my_btag = bt;         // tag at t = 64w+63
        bt = Mg[(size_t)b * 1024 + w * 32 + bt];
    }

    __syncthreads();                         // bp staging visible

    if (lane < 32) {
        const int w = lane;
        int tag = my_btag;
        int t = w * 64 + 63;
        int* ob = out + (size_t)b * TT;
        ob[t] = tag;
        #pragma unroll 1
        for (; t >= w * 64 + 1; --t) {
            tag = bp[(t - 1) * UU + tag];
            ob[t - 1] = tag;
        }
    }
}

// ---------------------------------------------------------------------------
extern "C" void kernel_launch(void* const* d_in, const int* in_sizes, int n_in,
                              void* d_out, int out_size, void* d_ws, size_t ws_size,
                              hipStream_t stream)
{
    const float* x     = (const float*)d_in[0];
    const float* K     = (const float*)d_in[1];
    const float* bias  = (const float*)d_in[2];
    const float* chain = (const float*)d_in[3];
    const float* lb    = (const float*)d_in[4];
    const float* rb    = (const float*)d_in[5];
    int* out = (int*)d_out;

    float* pot = (float*)d_ws;                          // 16 MB
    float* chk = pot + (size_t)BB * TT * UU;            // 64*33*32 floats = 264 KB
    unsigned char* Mg  = (unsigned char*)(chk + (size_t)BB * 33 * UU);  // 64 KB
    unsigned char* bpg = Mg + (size_t)BB * 32 * UU;     // 64*2047*32 = 4 MB

    potentials_kernel<<<512, 128, 0, stream>>>(x, K, bias, lb, rb, pot);
    vit_values_kernel<<<BB, 64, 0, stream>>>(pot, chain, chk);
    vit_window_kernel<<<dim3(32, BB), 64, 0, stream>>>(pot, chain, chk, Mg, bpg);
    vit_backtrack_kernel<<<BB, 64, 0, stream>>>(chk, Mg, bpg, out);
}